// Round 11
// baseline (104.090 us; speedup 1.0000x reference)
//
#include <hip/hip_runtime.h>

// CIN fused, d-contraction-first, R11: G=4, 71.5KB LDS -> 2 blocks/CU.
//   out1[b,h] = sum_d h1[b,h,d];  h1 = sum_{f,q} W0[h,fq] x[b,f,d] x[b,q,d]
//   out2[b,h] = sum_p W1[h,p] U[b,p];  U[b,(f,q)] = sum_d x[b,f,d] h1[b,q,d]
// 512 blocks x 512 thr (G=4 batch/block). Theory: at 1 block/CU (R6-R8) the
// phase barriers serialize the whole CU (~2x over pipe floor); with 2
// co-resident blocks one block's drains overlap the other's MFMA/L2 work
// (m114 mechanism). Phase-3 A-traffic doubles vs R8 -- R6-vs-R7 measured that
// axis as non-binding.
//   phase 1 : wave = m-tile t, 4 batches (verbatim R10 phaseA, verified)
//   phase 2a: out1, one shot
//   phase 2b: wave = (g, qh); U -> LDS Ub[f][g][q] (R8 imm-offset stores)
//   phase 3 : wave = t, full-K 156 chunks, 4 interleaved acc chains, N=4

#define F0   39
#define D_   16
#define H_   128
#define P0_  1521
#define P1_  4992
#define NF1  (F0 * 2 * 8)   // 624 layer-1 A-frags
#define NF2  (F0 * 4 * 8)   // 1248 W1 A-frags
#define SR4  72             // S_bf row stride (shorts; 144B, 16B-aligned)
#define UG4  136            // Ub g-stride (shorts; 272B: dw%32=4)
#define UF4  552            // Ub f-stride (shorts; 4*136+8 = 1104B, 16B-aligned)

typedef __attribute__((ext_vector_type(8))) short   short8;
typedef __attribute__((ext_vector_type(8))) __bf16  bf16x8;
typedef __attribute__((ext_vector_type(4))) float   floatx4;

__device__ __forceinline__ unsigned short bf16rne(float f) {
  unsigned int u = __float_as_uint(f);
  u += 0x7FFFu + ((u >> 16) & 1u);
  return (unsigned short)(u >> 16);
}

__device__ __forceinline__ floatx4 mfma16(short8 a, short8 b, floatx4 c) {
  return __builtin_amdgcn_mfma_f32_16x16x32_bf16(
      __builtin_bit_cast(bf16x8, a), __builtin_bit_cast(bf16x8, b), c, 0, 0, 0);
}

// ---------- pack W into MFMA A-frag order (verified R3-R10) ----------
__global__ __launch_bounds__(256) void pack_w_kernel(const float* __restrict__ w0,
                                                     const float* __restrict__ w1,
                                                     short8* __restrict__ wA1,
                                                     short8* __restrict__ wA2) {
  int id = blockIdx.x * 256 + threadIdx.x;
  union { short8 v; unsigned short e[8]; } pk;
  if (id < NF1 * 64) {
    int lane = id & 63, frag = id >> 6;
    int t = frag & 7, s = (frag >> 3) & 1, f = frag >> 4;
    int m = t * 16 + (lane & 15);
    int qb = s * 32 + (lane >> 4) * 8;
#pragma unroll
    for (int j = 0; j < 8; ++j) {
      int q = qb + j;
      float v = (q < F0) ? w0[(size_t)m * P0_ + f * F0 + q] : 0.f;
      pk.e[j] = bf16rne(v);
    }
    wA1[frag * 64 + lane] = pk.v;
  } else if (id < (NF1 + NF2) * 64) {
    int u = id - NF1 * 64;
    int lane = u & 63, frag = u >> 6;
    int t = frag & 7, s = (frag >> 3) & 3, f = frag >> 5;
    int m = t * 16 + (lane & 15);
    int pb = f * 128 + s * 32 + (lane >> 4) * 8;
#pragma unroll
    for (int j = 0; j < 8; ++j) pk.e[j] = bf16rne(w1[(size_t)m * P1_ + pb + j]);
    wA2[frag * 64 + lane] = pk.v;
  }
}

// ---------- fused main kernel, G=4, 2 blocks/CU ----------
__global__ __launch_bounds__(512, 4) void cin_fused_g4(const float* __restrict__ x,
                                                       const short8* __restrict__ wA1,
                                                       const short8* __restrict__ wA2,
                                                       float* __restrict__ out) {
  // LDS: [0,9984) xs fp32 | [9984,28416) S_bf | [28416,71472) xTb then Ub
  __shared__ __align__(16) char smem[9984 + 128 * SR4 * 2 + F0 * UF4 * 2];
  float (*xs)[F0][D_]  = (float (*)[F0][D_])smem;
  unsigned short* S_bf = (unsigned short*)(smem + 9984);
  unsigned short* xTb  = (unsigned short*)(smem + 9984 + 128 * SR4 * 2);
  unsigned short* Ub   = xTb;   // aliased; xTb dead after phase-1 reg loads

  const int tid  = threadIdx.x;
  const int lane = tid & 63;
  const int wv   = tid >> 6;      // 8 waves
  const int col  = lane & 15;
  const int quad = lane >> 4;
  const int b0   = blockIdx.x * 4;
  const floatx4 zf4 = {0.f, 0.f, 0.f, 0.f};

  // ---- stage x (coalesced float4) ----
  {
    const float4* xg = (const float4*)(x + (size_t)b0 * (F0 * D_));
    float4* xl = (float4*)smem;
    for (int i = tid; i < 4 * F0 * D_ / 4; i += 512) xl[i] = xg[i];
  }
  __syncthreads();

  // ---- xTb[g][q8][d][j] = bf16(x[g][q8*8+j][d]), zero-pad q>=39 ----
  {
    int i = tid;  // exactly 512 entries
    int d = i & 15, q8 = (i >> 4) & 7, g = i >> 7;
    union { short8 v; unsigned short e[8]; } pk;
#pragma unroll
    for (int j = 0; j < 8; ++j) {
      int q = q8 * 8 + j;
      pk.e[j] = (q < F0) ? bf16rne(xs[g][q][d]) : (unsigned short)0;
    }
    *(short8*)&xTb[(size_t)i * 8] = pk.v;
  }
  __syncthreads();

  // ===== phase 1: wave = m-tile t; 4 local batches (verbatim R10 phaseA) =====
  {
    const int t = wv;
    short8 bx[2][4];
#pragma unroll
    for (int s = 0; s < 2; ++s)
#pragma unroll
      for (int gi = 0; gi < 4; ++gi)
        bx[s][gi] = *(const short8*)&xTb[(size_t)(((gi * 8 + s * 4 + quad) * 16) + col) * 8];

    floatx4 acc2[4];
#pragma unroll
    for (int gi = 0; gi < 4; ++gi) acc2[gi] = zf4;

    short8 a0 = wA1[(size_t)(0 * 8 + t) * 64 + lane];
    short8 a1 = wA1[(size_t)(1 * 8 + t) * 64 + lane];
    for (int f = 0; f < F0; ++f) {
      int fn = (f + 1 < F0) ? f + 1 : f;
      short8 na0 = wA1[(size_t)((fn * 2 + 0) * 8 + t) * 64 + lane];
      short8 na1 = wA1[(size_t)((fn * 2 + 1) * 8 + t) * 64 + lane];
      float sx[4];
#pragma unroll
      for (int gi = 0; gi < 4; ++gi) sx[gi] = xs[gi][f][col];
#pragma unroll
      for (int gi = 0; gi < 4; ++gi) {
        floatx4 acf = mfma16(a0, bx[0][gi], zf4);
        acf = mfma16(a1, bx[1][gi], acf);
#pragma unroll
        for (int r = 0; r < 4; ++r) acc2[gi][r] += acf[r] * sx[gi];
      }
      a0 = na0; a1 = na1;
    }
    // NOTE: bx already consumed; xTb region free after the barrier below.
#pragma unroll
    for (int gi = 0; gi < 4; ++gi)
#pragma unroll
      for (int r = 0; r < 4; ++r)
        S_bf[(size_t)((t * 16 + quad * 4 + r) * SR4) + gi * 16 + col] =
            bf16rne(acc2[gi][r]);
  }
  __syncthreads();

  // ===== phase 2a: out1[b,h] = sum_d h1 (512 threads, one shot) =====
  {
    int h = tid & 127, g = tid >> 7;
    union { short8 v; unsigned int u[4]; } w0v, w1v;
    w0v.v = *(const short8*)&S_bf[(size_t)h * SR4 + g * 16];
    w1v.v = *(const short8*)&S_bf[(size_t)h * SR4 + g * 16 + 8];
    float sum = 0.f;
#pragma unroll
    for (int p = 0; p < 4; ++p) {
      sum += __uint_as_float(w0v.u[p] << 16) + __uint_as_float(w0v.u[p] & 0xFFFF0000u);
      sum += __uint_as_float(w1v.u[p] << 16) + __uint_as_float(w1v.u[p] & 0xFFFF0000u);
    }
    out[(size_t)(b0 + g) * 256 + h] = sum;
  }

  // ===== phase 2b: wave = (g, qh). U -> LDS Ub[f][g][q] =====
  // MFMA: A[m=f][k=d], B[n=q][k=d] -> C[m=f][n=q]  (R4/R10-verified mapping)
  {
    const int g  = wv & 3;
    const int qh = wv >> 2;
    short8 af[3];
#pragma unroll
    for (int ft = 0; ft < 3; ++ft) {
      union { short8 v; unsigned short e[8]; } pk;
      int f = ft * 16 + col;
      if (quad < 2 && f < F0) {
        const float* xp = &xs[g][f][quad * 8];
#pragma unroll
        for (int j = 0; j < 8; ++j) pk.e[j] = bf16rne(xp[j]);
      } else {
#pragma unroll
        for (int j = 0; j < 8; ++j) pk.e[j] = 0;
      }
      af[ft] = pk.v;
    }
#pragma unroll
    for (int qi = 0; qi < 4; ++qi) {
      const int qt = qh * 4 + qi;
      short8 bq;
      if (quad < 2) {
        bq = *(const short8*)&S_bf[(size_t)(qt * 16 + col) * SR4 + g * 16 + quad * 8];
      } else {
        bq = short8{0, 0, 0, 0, 0, 0, 0, 0};
      }
#pragma unroll
      for (int ft = 0; ft < 3; ++ft) {
        floatx4 c2 = mfma16(af[ft], bq, zf4);
        unsigned short* up =
            &Ub[(size_t)(ft * 16 + quad * 4) * UF4 + g * UG4 + qt * 16 + col];
        if (ft < 2) {
#pragma unroll
          for (int r = 0; r < 4; ++r) up[r * UF4] = bf16rne(c2[r]);
        } else {
#pragma unroll
          for (int r = 0; r < 4; ++r)
            if (32 + quad * 4 + r < F0) up[r * UF4] = bf16rne(c2[r]);
        }
      }
    }
  }
  __syncthreads();

  // ===== phase 3: wave = t; out2, full K (156 chunks), 4 acc chains =====
  // B-frag chunk c: k = quad*8+j over p = c*32+k -> f = c>>2, off = (c&3)*32
  {
    const int t = wv;
    const short8 zero8 = {0, 0, 0, 0, 0, 0, 0, 0};
    floatx4 aco[4];
#pragma unroll
    for (int i = 0; i < 4; ++i) aco[i] = zf4;
    short8 aW[4];
#pragma unroll
    for (int i = 0; i < 4; ++i) aW[i] = wA2[(size_t)(i * 8 + t) * 64 + lane];
    for (int cb = 0; cb < F0; ++cb) {
      int cn = (cb + 1 < F0) ? (cb + 1) * 4 : cb * 4;
      short8 nx[4];
#pragma unroll
      for (int i = 0; i < 4; ++i) nx[i] = wA2[(size_t)((cn + i) * 8 + t) * 64 + lane];
#pragma unroll
      for (int i = 0; i < 4; ++i) {
        int c = cb * 4 + i;
        short8 bU = (col < 4)
            ? *(const short8*)&Ub[(size_t)(c >> 2) * UF4 + col * UG4 + (c & 3) * 32 + quad * 8]
            : zero8;
        aco[i] = mfma16(aW[i], bU, aco[i]);
      }
#pragma unroll
      for (int i = 0; i < 4; ++i) aW[i] = nx[i];
    }
    if (col < 4) {
#pragma unroll
      for (int r = 0; r < 4; ++r) {
        float v = (aco[0][r] + aco[1][r]) + (aco[2][r] + aco[3][r]);
        out[(size_t)(b0 + col) * 256 + 128 + t * 16 + quad * 4 + r] = v;
      }
    }
  }
}

// ---------- fp32 last-resort fallback (known-correct R1 kernel) ----------
__global__ __launch_bounds__(128) void cin_fused_fallback(const float* __restrict__ x,
                                                          const float* __restrict__ w0,
                                                          const float* __restrict__ w1,
                                                          float* __restrict__ out) {
  __shared__ float4 xs4[F0 * D_ / 4];
  __shared__ float4 h1s4[H_ * D_ / 4];
  __shared__ float4 z4[H_ * D_ / 4];
  const int tid = threadIdx.x;
  const int b = blockIdx.x;
  const int hh = tid >> 2, dd = tid & 3, h0 = hh << 2;
  {
    const float4* xg = (const float4*)(x + (size_t)b * (F0 * D_));
    for (int i = tid; i < F0 * D_ / 4; i += 128) xs4[i] = xg[i];
  }
  __syncthreads();
  float acc[4][4];
#pragma unroll
  for (int i = 0; i < 4; ++i)
#pragma unroll
    for (int j = 0; j < 4; ++j) acc[i][j] = 0.f;
  for (int f = 0; f < F0; ++f) {
    for (int i = tid; i < F0 * D_ / 4; i += 128) {
      float4 xv = xs4[(f << 2) + (i & 3)], qv = xs4[i];
      z4[i] = make_float4(xv.x * qv.x, xv.y * qv.y, xv.z * qv.z, xv.w * qv.w);
    }
    __syncthreads();
    for (int q = 0; q < F0; ++q) {
      float4 zv = z4[(q << 2) + dd];
      int p = f * F0 + q;
      float ww[4] = {w0[(h0 + 0) * P0_ + p], w0[(h0 + 1) * P0_ + p],
                     w0[(h0 + 2) * P0_ + p], w0[(h0 + 3) * P0_ + p]};
      float zz[4] = {zv.x, zv.y, zv.z, zv.w};
#pragma unroll
      for (int hi = 0; hi < 4; ++hi)
#pragma unroll
        for (int di = 0; di < 4; ++di) acc[hi][di] += ww[hi] * zz[di];
    }
    __syncthreads();
  }
#pragma unroll
  for (int hi = 0; hi < 4; ++hi)
    h1s4[(h0 + hi) * 4 + dd] = make_float4(acc[hi][0], acc[hi][1], acc[hi][2], acc[hi][3]);
  __syncthreads();
  {
    float4 a0 = h1s4[tid * 4 + 0], a1 = h1s4[tid * 4 + 1];
    float4 a2 = h1s4[tid * 4 + 2], a3 = h1s4[tid * 4 + 3];
    out[(size_t)b * 256 + tid] = (a0.x + a0.y + a0.z + a0.w) + (a1.x + a1.y + a1.z + a1.w) +
                                 (a2.x + a2.y + a2.z + a2.w) + (a3.x + a3.y + a3.z + a3.w);
  }
#pragma unroll
  for (int i = 0; i < 4; ++i)
#pragma unroll
    for (int j = 0; j < 4; ++j) acc[i][j] = 0.f;
  for (int f = 0; f < F0; ++f) {
    for (int i = tid; i < H_ * D_ / 4; i += 128) {
      float4 xv = xs4[(f << 2) + (i & 3)], hv = h1s4[i];
      z4[i] = make_float4(xv.x * hv.x, xv.y * hv.y, xv.z * hv.z, xv.w * hv.w);
    }
    __syncthreads();
    for (int q = 0; q < H_; ++q) {
      float4 zv = z4[(q << 2) + dd];
      int p = f * H_ + q;
      float ww[4] = {w1[(h0 + 0) * P1_ + p], w1[(h0 + 1) * P1_ + p],
                     w1[(h0 + 2) * P1_ + p], w1[(h0 + 3) * P1_ + p]};
      float zz[4] = {zv.x, zv.y, zv.z, zv.w};
#pragma unroll
      for (int hi = 0; hi < 4; ++hi)
#pragma unroll
        for (int di = 0; di < 4; ++di) acc[hi][di] += ww[hi] * zz[di];
    }
    __syncthreads();
  }
#pragma unroll
  for (int hi = 0; hi < 4; ++hi)
    z4[(h0 + hi) * 4 + dd] = make_float4(acc[hi][0], acc[hi][1], acc[hi][2], acc[hi][3]);
  __syncthreads();
  {
    float4 a0 = z4[tid * 4 + 0], a1 = z4[tid * 4 + 1];
    float4 a2 = z4[tid * 4 + 2], a3 = z4[tid * 4 + 3];
    out[(size_t)b * 256 + 128 + tid] = (a0.x + a0.y + a0.z + a0.w) + (a1.x + a1.y + a1.z + a1.w) +
                                       (a2.x + a2.y + a2.z + a2.w) + (a3.x + a3.y + a3.z + a3.w);
  }
}

extern "C" void kernel_launch(void* const* d_in, const int* in_sizes, int n_in,
                              void* d_out, int out_size, void* d_ws, size_t ws_size,
                              hipStream_t stream) {
  const float* x  = (const float*)d_in[0];
  const float* w0 = (const float*)d_in[1];
  const float* w1 = (const float*)d_in[2];
  float* out = (float*)d_out;

  const size_t nfr    = (size_t)(NF1 + NF2) * 64;   // 119808 (frag,lane) pairs
  const size_t wbytes = nfr * sizeof(short8);       // ~1.92 MB

  if (ws_size >= wbytes) {
    short8* wA1 = (short8*)d_ws;
    short8* wA2 = wA1 + (size_t)NF1 * 64;
    pack_w_kernel<<<(int)((nfr + 255) / 256), 256, 0, stream>>>(w0, w1, wA1, wA2);
    cin_fused_g4<<<512, 512, 0, stream>>>(x, wA1, wA2, out);
  } else {
    cin_fused_fallback<<<2048, 128, 0, stream>>>(x, w0, w1, out);
  }
}

// Round 12
// 95.457 us; speedup vs baseline: 1.0904x; 1.0904x over previous
//
#include <hip/hip_runtime.h>

// CIN fused, d-contraction-first. R12 = R8 (best, 94.2us) + symmetric folding
// of W0: V0[h,f,q] = W0[h,fq] + W0[h,qf] for q>f, W0[h,ff] on diagonal;
// sum only q>=f. Layer-1 K-chunks per m-tile: 78 -> 46
//   f in [0,7):  2 chunks, windows q in [0,32), [32,64)   (q<f zeroed)
//   f in [7,39): 1 chunk, window q in [7,39) (exactly 32 wide, no pad)
// Phase-1 MFMA/CU 4992 -> 2944 (floor 10.1 -> 6.0us); wA1 624 -> 368 KB/block.
// Phases 2a/2b/3 verbatim R8 (verified).

#define F0   39
#define D_   16
#define H_   128
#define P0_  1521
#define P1_  4992
#define G8   8
#define NC1S 46             // folded layer-1 chunks
#define NF1S (NC1S * 8)     // 368 layer-1 A-frags
#define NF2  (F0 * 4 * 8)   // 1248 W1 A-frags
#define SROW 136            // S_bf row stride in shorts (272B, 16B-aligned)
#define UGS  136            // Ub2 g-stride in shorts
#define UFS  1096           // Ub2 f-stride in shorts (2192B, 16B-aligned)

typedef __attribute__((ext_vector_type(8))) short   short8;
typedef __attribute__((ext_vector_type(8))) __bf16  bf16x8;
typedef __attribute__((ext_vector_type(4))) float   floatx4;

__device__ __forceinline__ unsigned short bf16rne(float f) {
  unsigned int u = __float_as_uint(f);
  u += 0x7FFFu + ((u >> 16) & 1u);
  return (unsigned short)(u >> 16);
}

__device__ __forceinline__ floatx4 mfma16(short8 a, short8 b, floatx4 c) {
  return __builtin_amdgcn_mfma_f32_16x16x32_bf16(
      __builtin_bit_cast(bf16x8, a), __builtin_bit_cast(bf16x8, b), c, 0, 0, 0);
}

// ---------- pack W: wA1 = folded V0 chunks, wA2 unchanged (verified) ----------
__global__ __launch_bounds__(256) void pack_w_kernel(const float* __restrict__ w0,
                                                     const float* __restrict__ w1,
                                                     short8* __restrict__ wA1,
                                                     short8* __restrict__ wA2) {
  int id = blockIdx.x * 256 + threadIdx.x;
  union { short8 v; unsigned short e[8]; } pk;
  if (id < NF1S * 64) {
    int lane = id & 63, frag = id >> 6;
    int t = frag & 7, c = frag >> 3;
    int m = t * 16 + (lane & 15);
    int kb = (lane >> 4) * 8;
    int f, qbase;
    if (c < 14) { f = c >> 1; qbase = (c & 1) * 32 + kb; }
    else        { f = 7 + (c - 14); qbase = 7 + kb; }
#pragma unroll
    for (int j = 0; j < 8; ++j) {
      int q = qbase + j;
      float v = 0.f;
      if (q < F0 && q >= f) {
        v = w0[(size_t)m * P0_ + f * F0 + q];
        if (q > f) v += w0[(size_t)m * P0_ + q * F0 + f];
      }
      pk.e[j] = bf16rne(v);
    }
    wA1[frag * 64 + lane] = pk.v;
  } else if (id < (NF1S + NF2) * 64) {
    int u = id - NF1S * 64;
    int lane = u & 63, frag = u >> 6;
    int t = frag & 7, s = (frag >> 3) & 3, f = frag >> 5;
    int m = t * 16 + (lane & 15);
    int pb = f * 128 + s * 32 + (lane >> 4) * 8;
#pragma unroll
    for (int j = 0; j < 8; ++j) pk.e[j] = bf16rne(w1[(size_t)m * P1_ + pb + j]);
    wA2[frag * 64 + lane] = pk.v;
  }
}

// ---------- fused main kernel (R8 structure) ----------
__global__ __launch_bounds__(1024, 4) void cin_fused(const float* __restrict__ x,
                                                     const short8* __restrict__ wA1,
                                                     const short8* __restrict__ wA2,
                                                     float* __restrict__ out) {
  // LDS: [0,19968) xs fp32 (S32 in phase-3 reduce)
  //      [19968,+34816) S_bf | rest: xTb(16K)+xTb7(8K) then Ub2 (aliased)
  __shared__ __align__(16) char smem[19968 + 128 * SROW * 2 + F0 * UFS * 2];
  float (*xs)[F0][D_]   = (float (*)[F0][D_])smem;
  float* S32            = (float*)smem;
  unsigned short* S_bf  = (unsigned short*)(smem + 19968);
  unsigned short* xTb   = (unsigned short*)(smem + 19968 + 128 * SROW * 2);
  unsigned short* xTb7  = xTb + 8192;     // after xTb's 1024*8 shorts
  unsigned short* Ub2   = xTb;            // aliased; xTb/xTb7 dead by phase 2b

  const int tid  = threadIdx.x;
  const int lane = tid & 63;
  const int wv   = tid >> 6;      // 16 waves
  const int col  = lane & 15;
  const int quad = lane >> 4;
  const int b0   = blockIdx.x * G8;
  const floatx4 zf4 = {0.f, 0.f, 0.f, 0.f};

  // ---- stage x (coalesced float4) ----
  {
    const float4* xg = (const float4*)(x + (size_t)b0 * (F0 * D_));
    float4* xl = (float4*)smem;
    for (int i = tid; i < G8 * F0 * D_ / 4; i += 1024) xl[i] = xg[i];
  }
  __syncthreads();

  // ---- xTb[g][q8][d][j] = bf16(x[g][q8*8+j][d]), zero-pad q>=39 ----
  if (tid < G8 * 8 * D_) {
    int i = tid;
    int d = i & 15, q8 = (i >> 4) & 7, g = i >> 7;
    union { short8 v; unsigned short e[8]; } pk;
#pragma unroll
    for (int j = 0; j < 8; ++j) {
      int q = q8 * 8 + j;
      pk.e[j] = (q < F0) ? bf16rne(xs[g][q][d]) : (unsigned short)0;
    }
    *(short8*)&xTb[(size_t)i * 8] = pk.v;
  }
  // ---- xTb7[g][k8][d][j] = bf16(x[g][7+k8*8+j][d]); window [7,39), no pad ----
  if (tid < G8 * 4 * D_) {
    int i = tid;
    int d = i & 15, k8 = (i >> 4) & 3, g = i >> 6;
    union { short8 v; unsigned short e[8]; } pk;
#pragma unroll
    for (int j = 0; j < 8; ++j) pk.e[j] = bf16rne(xs[g][7 + k8 * 8 + j][d]);
    *(short8*)&xTb7[(size_t)i * 8] = pk.v;
  }
  __syncthreads();

  // ===== phase 1: wave = (gh, t); folded K-chunks =====
  {
    const int t  = wv & 7;
    const int g0 = (wv >> 3) * 4;

    short8 bx[2][4], bx7[4];
#pragma unroll
    for (int s = 0; s < 2; ++s)
#pragma unroll
      for (int gi = 0; gi < 4; ++gi)
        bx[s][gi] = *(const short8*)&xTb[(size_t)((((g0 + gi) * 8 + s * 4 + quad) * 16) + col) * 8];
#pragma unroll
    for (int gi = 0; gi < 4; ++gi)
      bx7[gi] = *(const short8*)&xTb7[(size_t)((((g0 + gi) * 4 + quad) * 16) + col) * 8];

    floatx4 acc2[4];
#pragma unroll
    for (int gi = 0; gi < 4; ++gi) acc2[gi] = zf4;

    short8 pa0 = wA1[(size_t)(0 * 8 + t) * 64 + lane];
    short8 pa1 = wA1[(size_t)(1 * 8 + t) * 64 + lane];
    // f in [0,7): two chunks (windows [0,32),[32,64))
    for (int f = 0; f < 7; ++f) {
      short8 a0 = pa0, a1 = pa1;
      int c0n = (f < 6) ? (2 * f + 2) : 14;
      int c1n = (f < 6) ? (2 * f + 3) : 15;
      pa0 = wA1[(size_t)(c0n * 8 + t) * 64 + lane];
      pa1 = wA1[(size_t)(c1n * 8 + t) * 64 + lane];
      float sx[4];
#pragma unroll
      for (int gi = 0; gi < 4; ++gi) sx[gi] = xs[g0 + gi][f][col];
#pragma unroll
      for (int gi = 0; gi < 4; ++gi) {
        floatx4 acf = mfma16(a0, bx[0][gi], zf4);
        acf = mfma16(a1, bx[1][gi], acf);
#pragma unroll
        for (int r = 0; r < 4; ++r) acc2[gi][r] += acf[r] * sx[gi];
      }
    }
    // f in [7,39): single chunk, window [7,39)
    for (int f = 7; f < F0; ++f) {
      short8 a = pa0;
      pa0 = pa1;
      int cn = 14 + (f - 7) + 2;
      if (cn > NC1S - 1) cn = NC1S - 1;
      pa1 = wA1[(size_t)(cn * 8 + t) * 64 + lane];
      float sx[4];
#pragma unroll
      for (int gi = 0; gi < 4; ++gi) sx[gi] = xs[g0 + gi][f][col];
#pragma unroll
      for (int gi = 0; gi < 4; ++gi) {
        floatx4 acf = mfma16(a, bx7[gi], zf4);
#pragma unroll
        for (int r = 0; r < 4; ++r) acc2[gi][r] += acf[r] * sx[gi];
      }
    }
    // h1 -> S_bf (bf16). Row = h, col = g*16+d.
#pragma unroll
    for (int gi = 0; gi < 4; ++gi)
#pragma unroll
      for (int r = 0; r < 4; ++r)
        S_bf[(size_t)((t * 16 + quad * 4 + r) * SROW) + (g0 + gi) * 16 + col] =
            bf16rne(acc2[gi][r]);
  }
  __syncthreads();

  // ===== phase 2a: out1[b,h] = sum_d h1 (1024 threads, one shot) =====
  {
    int h = tid & 127, g = tid >> 7;
    union { short8 v; unsigned int u[4]; } w0v, w1v;
    w0v.v = *(const short8*)&S_bf[(size_t)h * SROW + g * 16];
    w1v.v = *(const short8*)&S_bf[(size_t)h * SROW + g * 16 + 8];
    float sum = 0.f;
#pragma unroll
    for (int p = 0; p < 4; ++p) {
      sum += __uint_as_float(w0v.u[p] << 16) + __uint_as_float(w0v.u[p] & 0xFFFF0000u);
      sum += __uint_as_float(w1v.u[p] << 16) + __uint_as_float(w1v.u[p] & 0xFFFF0000u);
    }
    out[(size_t)(b0 + g) * 256 + h] = sum;
  }

  // ===== phase 2b: wave = (g, qh). U -> Ub2[f][g][q] (verbatim R8) =====
  {
    const int g  = wv & 7;
    const int qh = wv >> 3;
    short8 af[3];
#pragma unroll
    for (int ft = 0; ft < 3; ++ft) {
      union { short8 v; unsigned short e[8]; } pk;
      int f = ft * 16 + col;
      if (quad < 2 && f < F0) {
        const float* xp = &xs[g][f][quad * 8];
#pragma unroll
        for (int j = 0; j < 8; ++j) pk.e[j] = bf16rne(xp[j]);
      } else {
#pragma unroll
        for (int j = 0; j < 8; ++j) pk.e[j] = 0;
      }
      af[ft] = pk.v;
    }
#pragma unroll
    for (int qi = 0; qi < 4; ++qi) {
      const int qt = qh * 4 + qi;
      short8 bq;
      if (quad < 2) {
        bq = *(const short8*)&S_bf[(size_t)(qt * 16 + col) * SROW + g * 16 + quad * 8];
      } else {
        bq = short8{0, 0, 0, 0, 0, 0, 0, 0};
      }
#pragma unroll
      for (int ft = 0; ft < 3; ++ft) {
        floatx4 c2 = mfma16(af[ft], bq, zf4);
        unsigned short* up =
            &Ub2[(size_t)(ft * 16 + quad * 4) * UFS + g * UGS + qt * 16 + col];
        if (ft < 2) {
#pragma unroll
          for (int r = 0; r < 4; ++r) up[r * UFS] = bf16rne(c2[r]);
        } else {
#pragma unroll
          for (int r = 0; r < 4; ++r)
            if (32 + quad * 4 + r < F0) up[r * UFS] = bf16rne(c2[r]);
        }
      }
    }
  }
  __syncthreads();

  // ===== phase 3: wave = (t, kh). out2 (verbatim R8) =====
  {
    const int t   = wv & 7;
    const int kh  = wv >> 3;
    const int cb0 = kh ? 20 : 0;
    const int cbN = kh ? F0 : 20;
    const short8 zero8 = {0, 0, 0, 0, 0, 0, 0, 0};
    floatx4 aco[4];
#pragma unroll
    for (int i = 0; i < 4; ++i) aco[i] = zf4;
    short8 aW[4];
#pragma unroll
    for (int i = 0; i < 4; ++i) aW[i] = wA2[(size_t)((cb0 * 4 + i) * 8 + t) * 64 + lane];
    for (int cb = cb0; cb < cbN; ++cb) {
      int cn = (cb + 1 < cbN) ? cb + 1 : cb;
      short8 nx[4];
#pragma unroll
      for (int i = 0; i < 4; ++i) nx[i] = wA2[(size_t)((cn * 4 + i) * 8 + t) * 64 + lane];
      const unsigned short* ubase = &Ub2[(size_t)cb * UFS + col * UGS + quad * 8];
#pragma unroll
      for (int i = 0; i < 4; ++i) {
        short8 bU = (col < 8) ? *(const short8*)(ubase + i * 32) : zero8;
        aco[i] = mfma16(aW[i], bU, aco[i]);
      }
#pragma unroll
      for (int i = 0; i < 4; ++i) aW[i] = nx[i];
    }
    float v[4];
#pragma unroll
    for (int r = 0; r < 4; ++r)
      v[r] = (aco[0][r] + aco[1][r]) + (aco[2][r] + aco[3][r]);
    if (kh == 0 && col < 8) {
#pragma unroll
      for (int r = 0; r < 4; ++r)
        S32[(size_t)(t * 16 + quad * 4 + r) * 9 + col] = v[r];
    }
    __syncthreads();
    if (kh == 1 && col < 8) {
#pragma unroll
      for (int r = 0; r < 4; ++r) {
        int h = t * 16 + quad * 4 + r;
        out[(size_t)(b0 + col) * 256 + 128 + h] = v[r] + S32[(size_t)h * 9 + col];
      }
    }
  }
}

// ---------- fp32 last-resort fallback (known-correct R1 kernel) ----------
__global__ __launch_bounds__(128) void cin_fused_fallback(const float* __restrict__ x,
                                                          const float* __restrict__ w0,
                                                          const float* __restrict__ w1,
                                                          float* __restrict__ out) {
  __shared__ float4 xs4[F0 * D_ / 4];
  __shared__ float4 h1s4[H_ * D_ / 4];
  __shared__ float4 z4[H_ * D_ / 4];
  const int tid = threadIdx.x;
  const int b = blockIdx.x;
  const int hh = tid >> 2, dd = tid & 3, h0 = hh << 2;
  {
    const float4* xg = (const float4*)(x + (size_t)b * (F0 * D_));
    for (int i = tid; i < F0 * D_ / 4; i += 128) xs4[i] = xg[i];
  }
  __syncthreads();
  float acc[4][4];
#pragma unroll
  for (int i = 0; i < 4; ++i)
#pragma unroll
    for (int j = 0; j < 4; ++j) acc[i][j] = 0.f;
  for (int f = 0; f < F0; ++f) {
    for (int i = tid; i < F0 * D_ / 4; i += 128) {
      float4 xv = xs4[(f << 2) + (i & 3)], qv = xs4[i];
      z4[i] = make_float4(xv.x * qv.x, xv.y * qv.y, xv.z * qv.z, xv.w * qv.w);
    }
    __syncthreads();
    for (int q = 0; q < F0; ++q) {
      float4 zv = z4[(q << 2) + dd];
      int p = f * F0 + q;
      float ww[4] = {w0[(h0 + 0) * P0_ + p], w0[(h0 + 1) * P0_ + p],
                     w0[(h0 + 2) * P0_ + p], w0[(h0 + 3) * P0_ + p]};
      float zz[4] = {zv.x, zv.y, zv.z, zv.w};
#pragma unroll
      for (int hi = 0; hi < 4; ++hi)
#pragma unroll
        for (int di = 0; di < 4; ++di) acc[hi][di] += ww[hi] * zz[di];
    }
    __syncthreads();
  }
#pragma unroll
  for (int hi = 0; hi < 4; ++hi)
    h1s4[(h0 + hi) * 4 + dd] = make_float4(acc[hi][0], acc[hi][1], acc[hi][2], acc[hi][3]);
  __syncthreads();
  {
    float4 a0 = h1s4[tid * 4 + 0], a1 = h1s4[tid * 4 + 1];
    float4 a2 = h1s4[tid * 4 + 2], a3 = h1s4[tid * 4 + 3];
    out[(size_t)b * 256 + tid] = (a0.x + a0.y + a0.z + a0.w) + (a1.x + a1.y + a1.z + a1.w) +
                                 (a2.x + a2.y + a2.z + a2.w) + (a3.x + a3.y + a3.z + a3.w);
  }
#pragma unroll
  for (int i = 0; i < 4; ++i)
#pragma unroll
    for (int j = 0; j < 4; ++j) acc[i][j] = 0.f;
  for (int f = 0; f < F0; ++f) {
    for (int i = tid; i < H_ * D_ / 4; i += 128) {
      float4 xv = xs4[(f << 2) + (i & 3)], hv = h1s4[i];
      z4[i] = make_float4(xv.x * hv.x, xv.y * hv.y, xv.z * hv.z, xv.w * hv.w);
    }
    __syncthreads();
    for (int q = 0; q < H_; ++q) {
      float4 zv = z4[(q << 2) + dd];
      int p = f * H_ + q;
      float ww[4] = {w1[(h0 + 0) * P1_ + p], w1[(h0 + 1) * P1_ + p],
                     w1[(h0 + 2) * P1_ + p], w1[(h0 + 3) * P1_ + p]};
      float zz[4] = {zv.x, zv.y, zv.z, zv.w};
#pragma unroll
      for (int hi = 0; hi < 4; ++hi)
#pragma unroll
        for (int di = 0; di < 4; ++di) acc[hi][di] += ww[hi] * zz[di];
    }
    __syncthreads();
  }
#pragma unroll
  for (int hi = 0; hi < 4; ++hi)
    z4[(h0 + hi) * 4 + dd] = make_float4(acc[hi][0], acc[hi][1], acc[hi][2], acc[hi][3]);
  __syncthreads();
  {
    float4 a0 = z4[tid * 4 + 0], a1 = z4[tid * 4 + 1];
    float4 a2 = z4[tid * 4 + 2], a3 = z4[tid * 4 + 3];
    out[(size_t)b * 256 + 128 + tid] = (a0.x + a0.y + a0.z + a0.w) + (a1.x + a1.y + a1.z + a1.w) +
                                       (a2.x + a2.y + a2.z + a2.w) + (a3.x + a3.y + a3.z + a3.w);
  }
}

extern "C" void kernel_launch(void* const* d_in, const int* in_sizes, int n_in,
                              void* d_out, int out_size, void* d_ws, size_t ws_size,
                              hipStream_t stream) {
  const float* x  = (const float*)d_in[0];
  const float* w0 = (const float*)d_in[1];
  const float* w1 = (const float*)d_in[2];
  float* out = (float*)d_out;

  const size_t nfr    = (size_t)(NF1S + NF2) * 64;   // 103424 (frag,lane) pairs
  const size_t wbytes = nfr * sizeof(short8);        // ~1.65 MB

  if (ws_size >= wbytes) {
    short8* wA1 = (short8*)d_ws;
    short8* wA2 = wA1 + (size_t)NF1S * 64;
    pack_w_kernel<<<(int)((nfr + 255) / 256), 256, 0, stream>>>(w0, w1, wA1, wA2);
    cin_fused<<<256, 1024, 0, stream>>>(x, wA1, wA2, out);
  } else {
    cin_fused_fallback<<<2048, 128, 0, stream>>>(x, w0, w1, out);
  }
}